// Round 15
// baseline (185.316 us; speedup 1.0000x reference)
//
#include <hip/hip_runtime.h>
#include <hip/hip_bf16.h>

// B=2, T=2048, C=1024, NH=16, HD=64. fp32 I/O, bf16/f16 MFMA internals.
#define B_   2
#define T_   2048
#define C_   1024
#define NH_  16
#define HD_  64

typedef __attribute__((ext_vector_type(8))) short short8;       // 8 bf16 (MFMA A/B frag, K=32)
typedef __attribute__((ext_vector_type(4))) float float4_;      // MFMA C/D frag
typedef __attribute__((ext_vector_type(4))) _Float16 half4_;    // f16 MFMA A/B frag, K=16
typedef __attribute__((ext_vector_type(2))) __fp16  fp16x2;     // cvt_pkrtz native type
typedef __attribute__((ext_vector_type(4))) unsigned short ushort4_;

// softmax constants: p = exp2(QK*scale*log2e - 8*log2e); C1 folded into Q
// at gemm1's epilogue (R14, verified attn 58.5->54.9), C2 folded into the
// QK MFMA C-operand init.
#define SM_C1 0.18033688f      // 0.125 * log2(e)
#define SM_C2 11.5415603f      // 8 * log2(e)

static __device__ __forceinline__ unsigned short f2bf(float f) {
    union { float f; unsigned u; } v; v.f = f;
    unsigned r = v.u + 0x7fffu + ((v.u >> 16) & 1u);   // RNE
    return (unsigned short)(r >> 16);
}

// async global->LDS, 16B per lane: lane i lands at (wave-uniform base) + i*16B.
static __device__ __forceinline__ void g2l16(const void* g, void* l) {
    __builtin_amdgcn_global_load_lds(
        (const __attribute__((address_space(1))) void*)g,
        (__attribute__((address_space(3))) void*)l, 16, 0, 0);
}

// ---------------------------------------------------------------------------
// prep: one launch doing (1) x fp32->bf16 flat convert [blocks 0..2047],
// (2) w_attn transpose+convert [next 16*48], (3) w_proj transpose+convert
// [next 16*16]. All tiles 64x64, R=1024 rows for both weights.
// ---------------------------------------------------------------------------
__global__ __launch_bounds__(256) void prep(
    const float* __restrict__ x,      unsigned short* __restrict__ xb,
    const float* __restrict__ wA,     unsigned short* __restrict__ wTa,
    const float* __restrict__ wP,     unsigned short* __restrict__ wTp)
{
    const int t = threadIdx.x;
    int blk = blockIdx.x;
    if (blk < 2048) {                  // flat convert: 8 elems/thread
        int i = blk * 256 + t;
        const float4* p = (const float4*)x + (size_t)i * 2;
        float4 a = p[0], b = p[1];
        short8 o;
        o[0]=f2bf(a.x); o[1]=f2bf(a.y); o[2]=f2bf(a.z); o[3]=f2bf(a.w);
        o[4]=f2bf(b.x); o[5]=f2bf(b.y); o[6]=f2bf(b.z); o[7]=f2bf(b.w);
        *((short8*)xb + i) = o;
        return;
    }
    blk -= 2048;
    const float* in; unsigned short* out; int Cc;
    if (blk < 16 * 48) { in = wA; out = wTa; Cc = 3072; }
    else               { blk -= 16 * 48; in = wP; out = wTp; Cc = 1024; }
    const int r0 = (blk % 16) * 64, c0 = (blk / 16) * 64;
    const int R = 1024;
    __shared__ __align__(16) unsigned short Ts[64][72];
    #pragma unroll
    for (int cc = 0; cc < 2; ++cc) {
        int c = cc * 256 + t;
        int r = c >> 3, col = (c & 7) * 8;
        const float* p = in + (size_t)(r0 + r) * Cc + c0 + col;
        #pragma unroll
        for (int i = 0; i < 8; ++i) Ts[col + i][r] = f2bf(p[i]);
    }
    __syncthreads();
    #pragma unroll
    for (int cc = 0; cc < 2; ++cc) {
        int c = cc * 256 + t;
        int cr = c >> 3, oc = (c & 7) * 8;
        uint4 v = *(const uint4*)(&Ts[cr][oc]);
        *(uint4*)(out + (size_t)(c0 + cr) * R + r0 + oc) = v;
    }
}

// ---------------------------------------------------------------------------
// m97-structure GEMM, BK=64 (R7, verified): K=64 tile as TWO stacked
// [BM][32] half-tiles, 2 barriers per 64-K-step, 32 MFMA between.
// Epilogue (R9): scatter vt-store (L2-absorbed) + dead-write skip for
// v-blocks (bn>=16; attn reads V solely from vt).
// R14/R15: Q-blocks (WRITE_VT && bn<8) write Q PRE-SCALED by SM_C1, now
// behind the wave-uniform branch so K-blocks (bn 8..15) run the original
// epilogue byte-identically.
// (Failed/neutral ledger: R3 XCD swizzle, R8 LDS-transpose epilogue,
// R10 prep-swz + gemm2 BM128, R12 setprio, R13 dbuf-overlap.)
// ---------------------------------------------------------------------------
template <bool C_F32, int BM, bool WRITE_VT>
__global__ __launch_bounds__(256) void gemm_bt(
    const unsigned short* __restrict__ A,
    const unsigned short* __restrict__ Bt,
    void* __restrict__ Cv, unsigned short* __restrict__ vt,
    int M, int N, int K)
{
    __shared__ __align__(16) unsigned short As[2 * BM * 32];   // [kk][row][32]
    __shared__ __align__(16) unsigned short Bs[2 * 128 * 32];  // [kk][row][32]
    const int t = threadIdx.x, lane = t & 63, w = t >> 6;
    const int quad = lane >> 4, ln = lane & 15;
    const int bm = blockIdx.x, bn = blockIdx.y;
    constexpr int NI = (BM == 128) ? 4 : 2;
    const int mw = (BM == 128) ? (w & 1) * 64 : 0;
    const int nw = (BM == 128) ? (w >> 1) * 64 : w * 32;
    float4_ acc[4][NI] = {};

    constexpr int AROWS = BM / 4;      // rows of A staged per wave
    const unsigned short* Ag = A  + (size_t)(bm * BM + w * AROWS + (lane >> 2)) * K + (lane & 3) * 8;
    const unsigned short* Bg = Bt + (size_t)(bn * 128 + w * 32 + (lane >> 2)) * K + (lane & 3) * 8;
    unsigned short* lA = &As[(w * AROWS) * 32 + lane * 8];
    unsigned short* lB = &Bs[(w * 32) * 32 + lane * 8];

    for (int k0 = 0; k0 < K; k0 += 64) {
        // stage K=64 tile: per half kk, 16-row groups of 1024B per wave-call
        #pragma unroll
        for (int kk = 0; kk < 2; ++kk) {
            #pragma unroll
            for (int g = 0; g < AROWS / 16; ++g)
                g2l16(Ag + (size_t)g * 16 * K + k0 + kk * 32,
                      lA + kk * BM * 32 + g * 16 * 32);
            #pragma unroll
            for (int g = 0; g < 2; ++g)
                g2l16(Bg + (size_t)g * 16 * K + k0 + kk * 32,
                      lB + kk * 128 * 32 + g * 16 * 32);
        }
        __syncthreads();
        #pragma unroll
        for (int kk = 0; kk < 2; ++kk) {
            short8 a[4], b[NI];
            #pragma unroll
            for (int i = 0; i < 4; ++i)
                a[i] = *(const short8*)(&As[kk * BM * 32 + (mw + i * 16 + ln) * 32 + quad * 8]);
            #pragma unroll
            for (int i = 0; i < NI; ++i)
                b[i] = *(const short8*)(&Bs[kk * 128 * 32 + (nw + i * 16 + ln) * 32 + quad * 8]);
            #pragma unroll
            for (int mi = 0; mi < 4; ++mi)
                #pragma unroll
                for (int ni = 0; ni < NI; ++ni)
                    acc[mi][ni] = __builtin_amdgcn_mfma_f32_16x16x32_bf16(
                        a[mi], b[ni], acc[mi][ni], 0, 0, 0);
        }
        __syncthreads();
    }

    const int row0 = bm * BM + mw + quad * 4;
    const int col0 = bn * 128 + nw + ln;
    const bool vblk = WRITE_VT && (bn >= 16);   // whole block is V-part (cols>=2C)
    const bool qblk = WRITE_VT && (bn < 8);     // whole block is Q-part (pre-scale)
    #pragma unroll
    for (int mi = 0; mi < 4; ++mi)
        #pragma unroll
        for (int ni = 0; ni < NI; ++ni) {
            if (!vblk) {
                #pragma unroll
                for (int i = 0; i < 4; ++i) {
                    size_t idx = (size_t)(row0 + mi * 16 + i) * N + col0 + ni * 16;
                    float s = acc[mi][ni][i];
                    if (qblk) s *= SM_C1;       // uniform branch; K-blocks untouched
                    if (C_F32) ((float*)Cv)[idx] = s;
                    else       ((unsigned short*)Cv)[idx] = f2bf(s);
                }
            }
            if (vblk) {
                int d     = col0 + ni * 16 - 2 * C_;       // 0..1023
                int token = row0 + mi * 16;                // 4-aligned, +i
                int b     = token >> 11, tloc = token & 2047;
                union { fp16x2 h2[2]; ushort4_ u4; } pk;
                pk.h2[0] = __builtin_amdgcn_cvt_pkrtz(acc[mi][ni][0], acc[mi][ni][1]);
                pk.h2[1] = __builtin_amdgcn_cvt_pkrtz(acc[mi][ni][2], acc[mi][ni][3]);
                *(ushort4_*)(vt + ((size_t)b * 1024 + d) * T_ + tloc) = pk.u4;
            }
        }
}

// ---------------------------------------------------------------------------
// attn per-K-tile compute: QK^T (bf16 K=32 MFMA, swapped operands) ->
// in-register exp2 softmax numerator -> PV (f16 K=16 MFMA, P stays in regs).
// Ksb: bf16 [kk][d] (64x72). Vsb: f16 [d][kk] (64x72), XOR-8B swizzled.
// R14 (verified 58.5->54.9): Q arrives pre-scaled by SM_C1, QK accumulator
// initialized to -SM_C2 -> st is the finished exp2 argument; no per-element
// mul/sub (the -C2 shift cancels in the final 1/ls divide).
// ---------------------------------------------------------------------------
__device__ __forceinline__ void attn_tile(
    const unsigned short (*Ksb)[72], const unsigned short (*Vsb)[72],
    const short8 (&qf)[2][2], float4_ (&ot)[4][2], float (&ls)[2],
    int quad, int ln)
{
    half4_ pf[4][2];
    #pragma unroll
    for (int ct = 0; ct < 4; ++ct) {
        short8 kb0 = *(const short8*)(&Ksb[ct * 16 + ln][quad * 8]);
        short8 kb1 = *(const short8*)(&Ksb[ct * 16 + ln][32 + quad * 8]);
        #pragma unroll
        for (int qm = 0; qm < 2; ++qm) {
            float4_ st = {-SM_C2, -SM_C2, -SM_C2, -SM_C2};
            st = __builtin_amdgcn_mfma_f32_16x16x32_bf16(kb0, qf[qm][0], st, 0, 0, 0);
            st = __builtin_amdgcn_mfma_f32_16x16x32_bf16(kb1, qf[qm][1], st, 0, 0, 0);
            float p0 = __builtin_amdgcn_exp2f(st[0]);
            float p1 = __builtin_amdgcn_exp2f(st[1]);
            float p2 = __builtin_amdgcn_exp2f(st[2]);
            float p3 = __builtin_amdgcn_exp2f(st[3]);
            ls[qm] += (p0 + p1) + (p2 + p3);
            union { fp16x2 h2[2]; half4_ h4; } u;
            u.h2[0] = __builtin_amdgcn_cvt_pkrtz(p0, p1);
            u.h2[1] = __builtin_amdgcn_cvt_pkrtz(p2, p3);
            pf[ct][qm] = u.h4;
        }
    }
    // Ot += V^T P^T : A-frag = Vs[d=dt*16+ln][kk=ct*16+quad*4 ..+3]
    const char* vbase = (const char*)(&Vsb[0][0]);
    const int rsw = ln & 8;            // read-side addr XOR (row&8 == ln&8)
    #pragma unroll
    for (int dt = 0; dt < 4; ++dt) {
        int roff = (dt * 16 + ln) * 144;
        #pragma unroll
        for (int ct = 0; ct < 4; ++ct) {
            half4_ va = *(const half4_*)(vbase + roff + ((ct * 32 + quad * 8) ^ rsw));
            #pragma unroll
            for (int qm = 0; qm < 2; ++qm)
                ot[dt][qm] = __builtin_amdgcn_mfma_f32_16x16x16f16(
                    va, pf[ct][qm], ot[dt][qm], 0, 0, 0);
        }
    }
}

// ---------------------------------------------------------------------------
// Flash attention — R4 structure + R14 softmax fold (measured 54.9us,
// VGPR 108, no spill). 256 thr = 4 waves, 128-row Q-tile, wave w owns
// q-rows w*32..+31 (qm pair -> each K/V frag read feeds 2 MFMAs). K/V LDS
// double-buffered, ONE barrier per 64-token K-tile; regs prefetched a full
// iter ahead. R5/R6's 128-thr variant spilled; R1/R2 8-wave regressed;
// R12 setprio regressed. Vs swizzle kept (byte ^= row&8).
// ---------------------------------------------------------------------------
__global__ __launch_bounds__(256) void attn(
    const unsigned short* __restrict__ qkv,
    const unsigned short* __restrict__ vt,
    unsigned short* __restrict__ Y)
{
    __shared__ __align__(16) unsigned short Qs[128][72];     // bf16 [q][d]
    __shared__ __align__(16) unsigned short Ks[2][64][72];   // bf16 [kk][d]
    __shared__ __align__(16) unsigned short Vs[2][64][72];   // f16  [d][kk], swizzled

    const int t = threadIdx.x;
    const int qt = blockIdx.x, bh = blockIdx.y;
    const int b = bh >> 4, h = bh & 15;
    const int lane = t & 63, w = t >> 6;
    const int quad = lane >> 4, ln = lane & 15;

    const unsigned short* Qg  = qkv + (size_t)b * T_ * (3 * C_) + (size_t)h * HD_;
    const unsigned short* Kg  = Qg + C_;
    const unsigned short* Vtg = vt + (size_t)bh * HD_ * T_;

    // stage Q tile (128x64): 1024 chunks, 4/thread
    #pragma unroll
    for (int cc = 0; cc < 4; ++cc) {
        int c = cc * 256 + t;
        int r = c >> 3, col = (c & 7) * 8;
        *(uint4*)(&Qs[r][col]) = *(const uint4*)(Qg + (size_t)(qt * 128 + r) * (3 * C_) + col);
    }

    // K/V staging coords: thread t -> rows r0/r1, col c0v (16B each)
    const int r0 = t >> 3, c0v = (t & 7) * 8;
    const int r1 = r0 + 32;
    const int vsw = r0 & 8;            // write-side half-swap flag (r1&8 == r0&8)

    // tile loader / storer (regs <-> global / LDS)
    auto load_kv = [&](uint4& k0, uint4& k1, uint4& v0, uint4& v1, int kb) {
        k0 = *(const uint4*)(Kg + (size_t)(kb + r0) * (3 * C_) + c0v);
        k1 = *(const uint4*)(Kg + (size_t)(kb + r1) * (3 * C_) + c0v);
        v0 = *(const uint4*)(Vtg + (size_t)r0 * T_ + kb + c0v);
        v1 = *(const uint4*)(Vtg + (size_t)r1 * T_ + kb + c0v);
    };
    auto store_kv = [&](unsigned short (*Kb)[72], unsigned short (*Vb)[72],
                        uint4 k0, uint4 k1, uint4 v0, uint4 v1) {
        *(uint4*)(&Kb[r0][c0v]) = k0;
        *(uint4*)(&Kb[r1][c0v]) = k1;
        if (vsw) {
            uint4 s;
            s.x = v0.z; s.y = v0.w; s.z = v0.x; s.w = v0.y; v0 = s;
            s.x = v1.z; s.y = v1.w; s.z = v1.x; s.w = v1.y; v1 = s;
        }
        *(uint4*)(&Vb[r0][c0v]) = v0;
        *(uint4*)(&Vb[r1][c0v]) = v1;
    };

    // prefetch tile 0 into regA
    uint4 ka0, ka1, va0, va1, kb0r, kb1r, vb0r, vb1r;
    load_kv(ka0, ka1, va0, va1, 0);

    __syncthreads();                   // Q staged

    // hoisted Q frags: B-operand, lane holds Q[q=w*32+qm*16+ln][d=dh*32+quad*8..+7]
    short8 qf[2][2];
    #pragma unroll
    for (int qm = 0; qm < 2; ++qm)
        #pragma unroll
        for (int dh = 0; dh < 2; ++dh)
            qf[qm][dh] = *(const short8*)(&Qs[w * 32 + qm * 16 + ln][dh * 32 + quad * 8]);

    // tile0 -> buf0, prefetch tile1 -> regB
    store_kv(Ks[0], Vs[0], ka0, ka1, va0, va1);
    load_kv(kb0r, kb1r, vb0r, vb1r, 64);
    __syncthreads();                   // buf0 ready

    float4_ ot[4][2] = {};             // [dt][qm]: Ot[d=dt*16+quad*4+i][q=qm*16+ln]
    float ls[2] = {0.f, 0.f};

    constexpr int NT = T_ / 64;        // 32 K-tiles
    for (int it = 0; it < NT; it += 2) {
        // phase A: compute buf0 (tile it); write regB (tile it+1) -> buf1;
        // issue tile it+2 -> regA
        if (it + 1 < NT) store_kv(Ks[1], Vs[1], kb0r, kb1r, vb0r, vb1r);
        if (it + 2 < NT) load_kv(ka0, ka1, va0, va1, (it + 2) * 64);
        attn_tile(Ks[0], Vs[0], qf, ot, ls, quad, ln);
        __syncthreads();

        // phase B: compute buf1 (tile it+1); write regA (tile it+2) -> buf0;
        // issue tile it+3 -> regB
        if (it + 2 < NT) store_kv(Ks[0], Vs[0], ka0, ka1, va0, va1);
        if (it + 3 < NT) load_kv(kb0r, kb1r, vb0r, vb1r, (it + 3) * 64);
        if (it + 1 < NT) attn_tile(Ks[1], Vs[1], qf, ot, ls, quad, ln);
        __syncthreads();
    }

    // reduce ls across the 4 quads (lane bits 4,5)
    #pragma unroll
    for (int qm = 0; qm < 2; ++qm) {
        ls[qm] += __shfl_xor(ls[qm], 16, 64);
        ls[qm] += __shfl_xor(ls[qm], 32, 64);
    }

    // epilogue: Y[b, q, h*64 + d]; q = qt*128 + w*32 + qm*16 + ln
    #pragma unroll
    for (int qm = 0; qm < 2; ++qm) {
        unsigned short* Yr = Y + ((size_t)b * T_ + qt * 128 + w * 32 + qm * 16 + ln) * C_ + h * HD_;
        float inv = 1.0f / ls[qm];
        #pragma unroll
        for (int dt = 0; dt < 4; ++dt)
            #pragma unroll
            for (int i = 0; i < 4; ++i)
                Yr[dt * 16 + quad * 4 + i] = f2bf(ot[dt][qm][i] * inv);
    }
}

extern "C" void kernel_launch(void* const* d_in, const int* in_sizes, int n_in,
                              void* d_out, int out_size, void* d_ws, size_t ws_size,
                              hipStream_t stream)
{
    const float* x      = (const float*)d_in[0];   // [4096,1024]
    const float* w_attn = (const float*)d_in[1];   // [1024,3072]
    const float* w_proj = (const float*)d_in[2];   // [1024,1024]
    float* out = (float*)d_out;                    // [4096,1024]

    // ws (2B elems): qkv 12.58M | y/xb 4.19M | wTa 3.15M | wTp 1.05M | vt 4.19M
    unsigned short* qkv = (unsigned short*)d_ws;
    unsigned short* y   = qkv + (size_t)4096 * 3072;   // also xb (dead after gemm1)
    unsigned short* wTa = y   + (size_t)4096 * 1024;
    unsigned short* wTp = wTa + (size_t)3072 * 1024;
    unsigned short* vt  = wTp + (size_t)1024 * 1024;   // f16
    unsigned short* xb  = y;

    prep<<<2048 + 16 * 48 + 16 * 16, 256, 0, stream>>>(x, xb, w_attn, wTa, w_proj, wTp);

    gemm_bt<false, 128, true><<<dim3(32, 24), 256, 0, stream>>>(
        xb, wTa, qkv, vt, 4096, 3072, 1024);
    attn<<<dim3(16, 32), 256, 0, stream>>>(qkv, vt, y);
    gemm_bt<true, 64, false><<<dim3(64, 8), 256, 0, stream>>>(
        y, wTp, out, nullptr, 4096, 1024, 1024);
}

// Round 16
// 179.072 us; speedup vs baseline: 1.0349x; 1.0349x over previous
//
#include <hip/hip_runtime.h>
#include <hip/hip_bf16.h>

// B=2, T=2048, C=1024, NH=16, HD=64. fp32 I/O, bf16/f16 MFMA internals.
#define B_   2
#define T_   2048
#define C_   1024
#define NH_  16
#define HD_  64

typedef __attribute__((ext_vector_type(8))) short short8;       // 8 bf16 (MFMA A/B frag, K=32)
typedef __attribute__((ext_vector_type(4))) float float4_;      // MFMA C/D frag
typedef __attribute__((ext_vector_type(4))) _Float16 half4_;    // f16 MFMA A/B frag, K=16
typedef __attribute__((ext_vector_type(2))) __fp16  fp16x2;     // cvt_pkrtz native type
typedef __attribute__((ext_vector_type(4))) unsigned short ushort4_;

// softmax constants: p = exp2(QK*scale*log2e - 8*log2e).
// R16: C1 folded into w_attn's Q-COLUMNS in prep ((x·(w·C1)) == (x·w)·C1),
// so gemm1's epilogue stays byte-identical to the fast R13 form (R14/R15's
// epilogue-side fold cost ~5us — suspected VGPR/occupancy boundary in
// gemm1). C2 folded into attn's QK MFMA C-operand init (R14, verified
// attn 58.5->54.9).
#define SM_C1 0.18033688f      // 0.125 * log2(e)
#define SM_C2 11.5415603f      // 8 * log2(e)

static __device__ __forceinline__ unsigned short f2bf(float f) {
    union { float f; unsigned u; } v; v.f = f;
    unsigned r = v.u + 0x7fffu + ((v.u >> 16) & 1u);   // RNE
    return (unsigned short)(r >> 16);
}

// async global->LDS, 16B per lane: lane i lands at (wave-uniform base) + i*16B.
static __device__ __forceinline__ void g2l16(const void* g, void* l) {
    __builtin_amdgcn_global_load_lds(
        (const __attribute__((address_space(1))) void*)g,
        (__attribute__((address_space(3))) void*)l, 16, 0, 0);
}

// ---------------------------------------------------------------------------
// prep: one launch doing (1) x fp32->bf16 flat convert [blocks 0..2047],
// (2) w_attn transpose+convert [next 16*48], (3) w_proj transpose+convert
// [next 16*16]. All tiles 64x64, R=1024 rows for both weights.
// R16: wA blocks with c0 < 1024 (= Q output features) are pre-scaled by
// SM_C1 during the Ts write — memory-bound kernel, 16 muls/thread hide
// completely; K/V/wP paths multiply by exact 1.0f.
// ---------------------------------------------------------------------------
__global__ __launch_bounds__(256) void prep(
    const float* __restrict__ x,      unsigned short* __restrict__ xb,
    const float* __restrict__ wA,     unsigned short* __restrict__ wTa,
    const float* __restrict__ wP,     unsigned short* __restrict__ wTp)
{
    const int t = threadIdx.x;
    int blk = blockIdx.x;
    if (blk < 2048) {                  // flat convert: 8 elems/thread
        int i = blk * 256 + t;
        const float4* p = (const float4*)x + (size_t)i * 2;
        float4 a = p[0], b = p[1];
        short8 o;
        o[0]=f2bf(a.x); o[1]=f2bf(a.y); o[2]=f2bf(a.z); o[3]=f2bf(a.w);
        o[4]=f2bf(b.x); o[5]=f2bf(b.y); o[6]=f2bf(b.z); o[7]=f2bf(b.w);
        *((short8*)xb + i) = o;
        return;
    }
    blk -= 2048;
    const float* in; unsigned short* out; int Cc; bool isA;
    if (blk < 16 * 48) { in = wA; out = wTa; Cc = 3072; isA = true; }
    else               { blk -= 16 * 48; in = wP; out = wTp; Cc = 1024; isA = false; }
    const int r0 = (blk % 16) * 64, c0 = (blk / 16) * 64;
    const float qs = (isA && c0 < 1024) ? SM_C1 : 1.0f;   // Q-feature pre-scale
    const int R = 1024;
    __shared__ __align__(16) unsigned short Ts[64][72];
    #pragma unroll
    for (int cc = 0; cc < 2; ++cc) {
        int c = cc * 256 + t;
        int r = c >> 3, col = (c & 7) * 8;
        const float* p = in + (size_t)(r0 + r) * Cc + c0 + col;
        #pragma unroll
        for (int i = 0; i < 8; ++i) Ts[col + i][r] = f2bf(p[i] * qs);
    }
    __syncthreads();
    #pragma unroll
    for (int cc = 0; cc < 2; ++cc) {
        int c = cc * 256 + t;
        int cr = c >> 3, oc = (c & 7) * 8;
        uint4 v = *(const uint4*)(&Ts[cr][oc]);
        *(uint4*)(out + (size_t)(c0 + cr) * R + r0 + oc) = v;
    }
}

// ---------------------------------------------------------------------------
// m97-structure GEMM, BK=64 (R7, verified): K=64 tile as TWO stacked
// [BM][32] half-tiles, 2 barriers per 64-K-step, 32 MFMA between.
// Epilogue: R13/R9 form EXACTLY (scatter vt-store, L2-absorbed; dead-write
// skip for v-blocks bn>=16). R14/R15's epilogue-side Q-scale reverted —
// it cost ~5us (suspected gemm1 VGPR/occupancy boundary); the scale now
// lives in prep's weight conversion instead.
// (Failed/neutral ledger: R3 XCD swizzle, R8 LDS-transpose epilogue,
// R10 prep-swz + gemm2 BM128, R12 setprio, R13 dbuf-overlap.)
// ---------------------------------------------------------------------------
template <bool C_F32, int BM, bool WRITE_VT>
__global__ __launch_bounds__(256) void gemm_bt(
    const unsigned short* __restrict__ A,
    const unsigned short* __restrict__ Bt,
    void* __restrict__ Cv, unsigned short* __restrict__ vt,
    int M, int N, int K)
{
    __shared__ __align__(16) unsigned short As[2 * BM * 32];   // [kk][row][32]
    __shared__ __align__(16) unsigned short Bs[2 * 128 * 32];  // [kk][row][32]
    const int t = threadIdx.x, lane = t & 63, w = t >> 6;
    const int quad = lane >> 4, ln = lane & 15;
    const int bm = blockIdx.x, bn = blockIdx.y;
    constexpr int NI = (BM == 128) ? 4 : 2;
    const int mw = (BM == 128) ? (w & 1) * 64 : 0;
    const int nw = (BM == 128) ? (w >> 1) * 64 : w * 32;
    float4_ acc[4][NI] = {};

    constexpr int AROWS = BM / 4;      // rows of A staged per wave
    const unsigned short* Ag = A  + (size_t)(bm * BM + w * AROWS + (lane >> 2)) * K + (lane & 3) * 8;
    const unsigned short* Bg = Bt + (size_t)(bn * 128 + w * 32 + (lane >> 2)) * K + (lane & 3) * 8;
    unsigned short* lA = &As[(w * AROWS) * 32 + lane * 8];
    unsigned short* lB = &Bs[(w * 32) * 32 + lane * 8];

    for (int k0 = 0; k0 < K; k0 += 64) {
        // stage K=64 tile: per half kk, 16-row groups of 1024B per wave-call
        #pragma unroll
        for (int kk = 0; kk < 2; ++kk) {
            #pragma unroll
            for (int g = 0; g < AROWS / 16; ++g)
                g2l16(Ag + (size_t)g * 16 * K + k0 + kk * 32,
                      lA + kk * BM * 32 + g * 16 * 32);
            #pragma unroll
            for (int g = 0; g < 2; ++g)
                g2l16(Bg + (size_t)g * 16 * K + k0 + kk * 32,
                      lB + kk * 128 * 32 + g * 16 * 32);
        }
        __syncthreads();
        #pragma unroll
        for (int kk = 0; kk < 2; ++kk) {
            short8 a[4], b[NI];
            #pragma unroll
            for (int i = 0; i < 4; ++i)
                a[i] = *(const short8*)(&As[kk * BM * 32 + (mw + i * 16 + ln) * 32 + quad * 8]);
            #pragma unroll
            for (int i = 0; i < NI; ++i)
                b[i] = *(const short8*)(&Bs[kk * 128 * 32 + (nw + i * 16 + ln) * 32 + quad * 8]);
            #pragma unroll
            for (int mi = 0; mi < 4; ++mi)
                #pragma unroll
                for (int ni = 0; ni < NI; ++ni)
                    acc[mi][ni] = __builtin_amdgcn_mfma_f32_16x16x32_bf16(
                        a[mi], b[ni], acc[mi][ni], 0, 0, 0);
        }
        __syncthreads();
    }

    const int row0 = bm * BM + mw + quad * 4;
    const int col0 = bn * 128 + nw + ln;
    const bool vblk = WRITE_VT && (bn >= 16);   // whole block is V-part (cols>=2C)
    #pragma unroll
    for (int mi = 0; mi < 4; ++mi)
        #pragma unroll
        for (int ni = 0; ni < NI; ++ni) {
            if (!vblk) {
                #pragma unroll
                for (int i = 0; i < 4; ++i) {
                    size_t idx = (size_t)(row0 + mi * 16 + i) * N + col0 + ni * 16;
                    if (C_F32) ((float*)Cv)[idx] = acc[mi][ni][i];
                    else       ((unsigned short*)Cv)[idx] = f2bf(acc[mi][ni][i]);
                }
            }
            if (vblk) {
                int d     = col0 + ni * 16 - 2 * C_;       // 0..1023
                int token = row0 + mi * 16;                // 4-aligned, +i
                int b     = token >> 11, tloc = token & 2047;
                union { fp16x2 h2[2]; ushort4_ u4; } pk;
                pk.h2[0] = __builtin_amdgcn_cvt_pkrtz(acc[mi][ni][0], acc[mi][ni][1]);
                pk.h2[1] = __builtin_amdgcn_cvt_pkrtz(acc[mi][ni][2], acc[mi][ni][3]);
                *(ushort4_*)(vt + ((size_t)b * 1024 + d) * T_ + tloc) = pk.u4;
            }
        }
}

// ---------------------------------------------------------------------------
// attn per-K-tile compute: QK^T (bf16 K=32 MFMA, swapped operands) ->
// in-register exp2 softmax numerator -> PV (f16 K=16 MFMA, P stays in regs).
// Ksb: bf16 [kk][d] (64x72). Vsb: f16 [d][kk] (64x72), XOR-8B swizzled.
// R14 (verified 58.5->54.9): Q arrives pre-scaled by SM_C1 (now via prep's
// weight fold), QK accumulator initialized to -SM_C2 -> st is the finished
// exp2 argument; no per-element mul/sub (the -C2 shift cancels in the
// final 1/ls divide).
// ---------------------------------------------------------------------------
__device__ __forceinline__ void attn_tile(
    const unsigned short (*Ksb)[72], const unsigned short (*Vsb)[72],
    const short8 (&qf)[2][2], float4_ (&ot)[4][2], float (&ls)[2],
    int quad, int ln)
{
    half4_ pf[4][2];
    #pragma unroll
    for (int ct = 0; ct < 4; ++ct) {
        short8 kb0 = *(const short8*)(&Ksb[ct * 16 + ln][quad * 8]);
        short8 kb1 = *(const short8*)(&Ksb[ct * 16 + ln][32 + quad * 8]);
        #pragma unroll
        for (int qm = 0; qm < 2; ++qm) {
            float4_ st = {-SM_C2, -SM_C2, -SM_C2, -SM_C2};
            st = __builtin_amdgcn_mfma_f32_16x16x32_bf16(kb0, qf[qm][0], st, 0, 0, 0);
            st = __builtin_amdgcn_mfma_f32_16x16x32_bf16(kb1, qf[qm][1], st, 0, 0, 0);
            float p0 = __builtin_amdgcn_exp2f(st[0]);
            float p1 = __builtin_amdgcn_exp2f(st[1]);
            float p2 = __builtin_amdgcn_exp2f(st[2]);
            float p3 = __builtin_amdgcn_exp2f(st[3]);
            ls[qm] += (p0 + p1) + (p2 + p3);
            union { fp16x2 h2[2]; half4_ h4; } u;
            u.h2[0] = __builtin_amdgcn_cvt_pkrtz(p0, p1);
            u.h2[1] = __builtin_amdgcn_cvt_pkrtz(p2, p3);
            pf[ct][qm] = u.h4;
        }
    }
    // Ot += V^T P^T : A-frag = Vs[d=dt*16+ln][kk=ct*16+quad*4 ..+3]
    const char* vbase = (const char*)(&Vsb[0][0]);
    const int rsw = ln & 8;            // read-side addr XOR (row&8 == ln&8)
    #pragma unroll
    for (int dt = 0; dt < 4; ++dt) {
        int roff = (dt * 16 + ln) * 144;
        #pragma unroll
        for (int ct = 0; ct < 4; ++ct) {
            half4_ va = *(const half4_*)(vbase + roff + ((ct * 32 + quad * 8) ^ rsw));
            #pragma unroll
            for (int qm = 0; qm < 2; ++qm)
                ot[dt][qm] = __builtin_amdgcn_mfma_f32_16x16x16f16(
                    va, pf[ct][qm], ot[dt][qm], 0, 0, 0);
        }
    }
}

// ---------------------------------------------------------------------------
// Flash attention — R4 structure + R14 softmax fold (measured 54.9-55.5us,
// VGPR 108, no spill). 256 thr = 4 waves, 128-row Q-tile, wave w owns
// q-rows w*32..+31 (qm pair -> each K/V frag read feeds 2 MFMAs). K/V LDS
// double-buffered, ONE barrier per 64-token K-tile; regs prefetched a full
// iter ahead. R5/R6's 128-thr variant spilled; R1/R2 8-wave regressed;
// R12 setprio regressed. Vs swizzle kept (byte ^= row&8).
// ---------------------------------------------------------------------------
__global__ __launch_bounds__(256) void attn(
    const unsigned short* __restrict__ qkv,
    const unsigned short* __restrict__ vt,
    unsigned short* __restrict__ Y)
{
    __shared__ __align__(16) unsigned short Qs[128][72];     // bf16 [q][d]
    __shared__ __align__(16) unsigned short Ks[2][64][72];   // bf16 [kk][d]
    __shared__ __align__(16) unsigned short Vs[2][64][72];   // f16  [d][kk], swizzled

    const int t = threadIdx.x;
    const int qt = blockIdx.x, bh = blockIdx.y;
    const int b = bh >> 4, h = bh & 15;
    const int lane = t & 63, w = t >> 6;
    const int quad = lane >> 4, ln = lane & 15;

    const unsigned short* Qg  = qkv + (size_t)b * T_ * (3 * C_) + (size_t)h * HD_;
    const unsigned short* Kg  = Qg + C_;
    const unsigned short* Vtg = vt + (size_t)bh * HD_ * T_;

    // stage Q tile (128x64): 1024 chunks, 4/thread
    #pragma unroll
    for (int cc = 0; cc < 4; ++cc) {
        int c = cc * 256 + t;
        int r = c >> 3, col = (c & 7) * 8;
        *(uint4*)(&Qs[r][col]) = *(const uint4*)(Qg + (size_t)(qt * 128 + r) * (3 * C_) + col);
    }

    // K/V staging coords: thread t -> rows r0/r1, col c0v (16B each)
    const int r0 = t >> 3, c0v = (t & 7) * 8;
    const int r1 = r0 + 32;
    const int vsw = r0 & 8;            // write-side half-swap flag (r1&8 == r0&8)

    // tile loader / storer (regs <-> global / LDS)
    auto load_kv = [&](uint4& k0, uint4& k1, uint4& v0, uint4& v1, int kb) {
        k0 = *(const uint4*)(Kg + (size_t)(kb + r0) * (3 * C_) + c0v);
        k1 = *(const uint4*)(Kg + (size_t)(kb + r1) * (3 * C_) + c0v);
        v0 = *(const uint4*)(Vtg + (size_t)r0 * T_ + kb + c0v);
        v1 = *(const uint4*)(Vtg + (size_t)r1 * T_ + kb + c0v);
    };
    auto store_kv = [&](unsigned short (*Kb)[72], unsigned short (*Vb)[72],
                        uint4 k0, uint4 k1, uint4 v0, uint4 v1) {
        *(uint4*)(&Kb[r0][c0v]) = k0;
        *(uint4*)(&Kb[r1][c0v]) = k1;
        if (vsw) {
            uint4 s;
            s.x = v0.z; s.y = v0.w; s.z = v0.x; s.w = v0.y; v0 = s;
            s.x = v1.z; s.y = v1.w; s.z = v1.x; s.w = v1.y; v1 = s;
        }
        *(uint4*)(&Vb[r0][c0v]) = v0;
        *(uint4*)(&Vb[r1][c0v]) = v1;
    };

    // prefetch tile 0 into regA
    uint4 ka0, ka1, va0, va1, kb0r, kb1r, vb0r, vb1r;
    load_kv(ka0, ka1, va0, va1, 0);

    __syncthreads();                   // Q staged

    // hoisted Q frags: B-operand, lane holds Q[q=w*32+qm*16+ln][d=dh*32+quad*8..+7]
    short8 qf[2][2];
    #pragma unroll
    for (int qm = 0; qm < 2; ++qm)
        #pragma unroll
        for (int dh = 0; dh < 2; ++dh)
            qf[qm][dh] = *(const short8*)(&Qs[w * 32 + qm * 16 + ln][dh * 32 + quad * 8]);

    // tile0 -> buf0, prefetch tile1 -> regB
    store_kv(Ks[0], Vs[0], ka0, ka1, va0, va1);
    load_kv(kb0r, kb1r, vb0r, vb1r, 64);
    __syncthreads();                   // buf0 ready

    float4_ ot[4][2] = {};             // [dt][qm]: Ot[d=dt*16+quad*4+i][q=qm*16+ln]
    float ls[2] = {0.f, 0.f};

    constexpr int NT = T_ / 64;        // 32 K-tiles
    for (int it = 0; it < NT; it += 2) {
        // phase A: compute buf0 (tile it); write regB (tile it+1) -> buf1;
        // issue tile it+2 -> regA
        if (it + 1 < NT) store_kv(Ks[1], Vs[1], kb0r, kb1r, vb0r, vb1r);
        if (it + 2 < NT) load_kv(ka0, ka1, va0, va1, (it + 2) * 64);
        attn_tile(Ks[0], Vs[0], qf, ot, ls, quad, ln);
        __syncthreads();

        // phase B: compute buf1 (tile it+1); write regA (tile it+2) -> buf0;
        // issue tile it+3 -> regB
        if (it + 2 < NT) store_kv(Ks[0], Vs[0], ka0, ka1, va0, va1);
        if (it + 3 < NT) load_kv(kb0r, kb1r, vb0r, vb1r, (it + 3) * 64);
        if (it + 1 < NT) attn_tile(Ks[1], Vs[1], qf, ot, ls, quad, ln);
        __syncthreads();
    }

    // reduce ls across the 4 quads (lane bits 4,5)
    #pragma unroll
    for (int qm = 0; qm < 2; ++qm) {
        ls[qm] += __shfl_xor(ls[qm], 16, 64);
        ls[qm] += __shfl_xor(ls[qm], 32, 64);
    }

    // epilogue: Y[b, q, h*64 + d]; q = qt*128 + w*32 + qm*16 + ln
    #pragma unroll
    for (int qm = 0; qm < 2; ++qm) {
        unsigned short* Yr = Y + ((size_t)b * T_ + qt * 128 + w * 32 + qm * 16 + ln) * C_ + h * HD_;
        float inv = 1.0f / ls[qm];
        #pragma unroll
        for (int dt = 0; dt < 4; ++dt)
            #pragma unroll
            for (int i = 0; i < 4; ++i)
                Yr[dt * 16 + quad * 4 + i] = f2bf(ot[dt][qm][i] * inv);
    }
}

extern "C" void kernel_launch(void* const* d_in, const int* in_sizes, int n_in,
                              void* d_out, int out_size, void* d_ws, size_t ws_size,
                              hipStream_t stream)
{
    const float* x      = (const float*)d_in[0];   // [4096,1024]
    const float* w_attn = (const float*)d_in[1];   // [1024,3072]
    const float* w_proj = (const float*)d_in[2];   // [1024,1024]
    float* out = (float*)d_out;                    // [4096,1024]

    // ws (2B elems): qkv 12.58M | y/xb 4.19M | wTa 3.15M | wTp 1.05M | vt 4.19M
    unsigned short* qkv = (unsigned short*)d_ws;
    unsigned short* y   = qkv + (size_t)4096 * 3072;   // also xb (dead after gemm1)
    unsigned short* wTa = y   + (size_t)4096 * 1024;
    unsigned short* wTp = wTa + (size_t)3072 * 1024;
    unsigned short* vt  = wTp + (size_t)1024 * 1024;   // f16
    unsigned short* xb  = y;

    prep<<<2048 + 16 * 48 + 16 * 16, 256, 0, stream>>>(x, xb, w_attn, wTa, w_proj, wTp);

    gemm_bt<false, 128, true><<<dim3(32, 24), 256, 0, stream>>>(
        xb, wTa, qkv, vt, 4096, 3072, 1024);
    attn<<<dim3(16, 32), 256, 0, stream>>>(qkv, vt, y);
    gemm_bt<true, 64, false><<<dim3(64, 8), 256, 0, stream>>>(
        y, wTp, out, nullptr, 4096, 1024, 1024);
}